// Round 13
// baseline (57.423 us; speedup 1.0000x reference)
//
#include <hip/hip_runtime.h>

// NW kernel regression, fused pairwise evaluation — polynomial weight, no LUT.
// queries [N,3] f32, keys [M,3] f32, values [M,8] f32, kernelLen [1] f32
// out [N,8] f32 = (K @ V) / (K @ 1) + 1e-6,
// w(d) = max(0,(2+cos(2*pi*d))*(1-d)/3 + sin(2*pi*d)/(2*pi)), d = |q-k|/L
//
// Round-13: round-11 skeleton (s_load k/v via readfirstlane, partials+reduce)
// with the LDS LUT replaced by a packed polynomial: t=2d-1, u=t^2,
//   w = C2(u)*(1-t) - S2(u)*t,  C2=(2-cos(pi t))/6,  S2*t = sin(pi t)/(2pi)
// (exact Taylor coeffs, |err|<=3.5e-5; d=min(d,1) -> t=1 -> w=max(-3e-6,0)=0
// exactly beyond the clamp). Kills the round-9 lgkm stall (s_load+ds_read
// shared counter) and the 5.2M LUT bank-conflict cycles: hot loop has NO LDS.
// Keys pre-scaled by prep kernel to [-2k*invL^2 | |k|^2*invL^2] pairs so
// d^2*invL^2 = 4 pk-ops (expansion form, max(,0) guard like the reference).
// KSB 1024 (nsb=8): halves partial traffic; 1024 blocks = 8192 waves.

typedef float v2f __attribute__((ext_vector_type(2)));

#define NCH 8
#define QG 64          // queries per block (= lanes per wave)
#define KSB 1024       // keys per block
#define TPB 512        // threads per block
#define NWAVE 8
#define KPW (KSB / NWAVE)   // keys per wave = 128
#define PPW (KPW / 2)       // key pairs per wave = 64

__device__ __forceinline__ float nw_weight_exact(float cd) {
    float r  = __builtin_amdgcn_fractf(cd);
    float sn = __builtin_amdgcn_sinf(r);
    float cs = __builtin_amdgcn_cosf(r);
    float t  = (1.0f - cd) * (1.0f / 3.0f);
    float wt = fmaf(sn, 0.15915494309189535f, fmaf(cs, t, t + t));
    return fmaxf(wt, 0.0f);
}

// pack key pair p: [-2*ss*x0,-2*ss*x1, -2*ss*y0,-2*ss*y1, -2*ss*z0,-2*ss*z1,
//                   ss*|k0|^2, ss*|k1|^2], ss = invL^2
__global__ __launch_bounds__(256) void nw_prep(const float* __restrict__ k,
                                               const float* __restrict__ kl,
                                               float* __restrict__ kprep, int npair) {
    const int p = blockIdx.x * 256 + threadIdx.x;
    if (p >= npair) return;
    const float iL = 1.0f / kl[0];
    const float ss = iL * iL;
    const float x0 = k[(size_t)(2 * p) * 3 + 0], y0 = k[(size_t)(2 * p) * 3 + 1], z0 = k[(size_t)(2 * p) * 3 + 2];
    const float x1 = k[(size_t)(2 * p) * 3 + 3], y1 = k[(size_t)(2 * p) * 3 + 4], z1 = k[(size_t)(2 * p) * 3 + 5];
    float* o = kprep + (size_t)p * 8;
    o[0] = -2.0f * ss * x0; o[1] = -2.0f * ss * x1;
    o[2] = -2.0f * ss * y0; o[3] = -2.0f * ss * y1;
    o[4] = -2.0f * ss * z0; o[5] = -2.0f * ss * z1;
    o[6] = ss * fmaf(x0, x0, fmaf(y0, y0, z0 * z0));
    o[7] = ss * fmaf(x1, x1, fmaf(y1, y1, z1 * z1));
}

__global__ __launch_bounds__(TPB) void nw_main(const float* __restrict__ q,
                                               const float* __restrict__ kprep,
                                               const float* __restrict__ v,
                                               const float* __restrict__ kl,
                                               float* __restrict__ part,
                                               int N) {
    __shared__ float red[TPB * 10];    // cross-wave reduce buffer (only LDS use)

    const int tid  = threadIdx.x;
    const int lane = tid & 63;
    const int wid  = tid >> 6;
    const int qg   = blockIdx.x;
    const int sb   = blockIdx.y;

    const float iL = 1.0f / kl[0];
    const float ss = iL * iL;

    const int i = qg * QG + lane;
    const float qx = q[i * 3 + 0];
    const float qy = q[i * 3 + 1];
    const float qz = q[i * 3 + 2];
    const float Q2 = ss * fmaf(qx, qx, fmaf(qy, qy, qz * qz));

    const v2f qxp = {qx, qx}, qyp = {qy, qy}, qzp = {qz, qz}, Q2p = {Q2, Q2};

    // polynomial coefficients (exact Taylor in pi), packed
    const v2f C0 = {0.16666667f, 0.16666667f};
    const v2f C1 = {0.82246703f, 0.82246703f};
    const v2f C2c = {-0.67645202f, -0.67645202f};
    const v2f C3 = {0.22254379f, 0.22254379f};
    const v2f C4 = {-0.03922177f, -0.03922177f};
    const v2f C5 = {0.00430115f, 0.00430115f};
    const v2f C6 = {-3.21596e-4f, -3.21596e-4f};
    const v2f S0 = {0.5f, 0.5f};
    const v2f S1 = {-0.82246703f, -0.82246703f};
    const v2f S2c = {0.40587121f, 0.40587121f};
    const v2f S3 = {-0.09537591f, -0.09537591f};
    const v2f S4 = {0.01307394f, 0.01307394f};
    const v2f S5 = {-0.00117304f, -0.00117304f};
    const v2f S6 = {7.42144e-5f, 7.42144e-5f};
    const v2f two2 = {2.0f, 2.0f}, mone2 = {-1.0f, -1.0f}, one2 = {1.0f, 1.0f};

    // wave-uniform pair base in SGPR -> kprep/v loads scalarize to s_load
    const int uwid = __builtin_amdgcn_readfirstlane(wid);
    const int pbase = sb * (KSB / 2) + uwid * PPW;
    const float* __restrict__ kpp = kprep + (size_t)pbase * 8;
    const float* __restrict__ vp  = v + (size_t)(2 * pbase) * 8;

    v2f acc4[4];
#pragma unroll
    for (int c = 0; c < 4; ++c) acc4[c] = v2f{0.0f, 0.0f};
    v2f den2 = {0.0f, 0.0f};

#pragma unroll 4
    for (int p = 0; p < PPW; ++p) {
        const v2f KX = *(const v2f*)(kpp + (size_t)p * 8 + 0);
        const v2f KY = *(const v2f*)(kpp + (size_t)p * 8 + 2);
        const v2f KZ = *(const v2f*)(kpp + (size_t)p * 8 + 4);
        const v2f K2 = *(const v2f*)(kpp + (size_t)p * 8 + 6);

        v2f d2 = K2 + Q2p;
        d2 += KX * qxp;                 // v_pk_fma_f32
        d2 += KY * qyp;
        d2 += KZ * qzp;
        d2.x = fmaxf(d2.x, 0.0f);       // expansion can go -1e-7 (ref does max too)
        d2.y = fmaxf(d2.y, 0.0f);
        v2f d;
        d.x = __builtin_amdgcn_sqrtf(d2.x);
        d.y = __builtin_amdgcn_sqrtf(d2.y);
        d.x = fminf(d.x, 1.0f);         // w == 0 beyond d=1 (poly hits exact 0)
        d.y = fminf(d.y, 1.0f);

        const v2f t = d * two2 + mone2; // t = 2d-1
        const v2f u = t * t;
        v2f c = C6;
        c = c * u + C5; c = c * u + C4; c = c * u + C3;
        c = c * u + C2c; c = c * u + C1; c = c * u + C0;
        v2f s = S6;
        s = s * u + S5; s = s * u + S4; s = s * u + S3;
        s = s * u + S2c; s = s * u + S1; s = s * u + S0;
        const v2f st  = s * t;
        const v2f omt = one2 - t;
        v2f w = c * omt - st;
        w.x = fmaxf(w.x, 0.0f);
        w.y = fmaxf(w.y, 0.0f);

        den2 += w;
        const v2f wa = {w.x, w.x}, wb = {w.y, w.y};
        const v2f* va = (const v2f*)(vp + (size_t)(2 * p) * 8);
        const v2f* vb = (const v2f*)(vp + (size_t)(2 * p + 1) * 8);
        acc4[0] += wa * va[0];
        acc4[1] += wa * va[1];
        acc4[2] += wa * va[2];
        acc4[3] += wa * va[3];
        acc4[0] += wb * vb[0];
        acc4[1] += wb * vb[1];
        acc4[2] += wb * vb[2];
        acc4[3] += wb * vb[3];
    }
    const float den = den2.x + den2.y;

    __syncthreads();
    {
        float vals[10] = {acc4[0].x, acc4[0].y, acc4[1].x, acc4[1].y,
                          acc4[2].x, acc4[2].y, acc4[3].x, acc4[3].y, den, 0.0f};
        float* r = red + (size_t)(wid * 64 + lane) * 10;
#pragma unroll
        for (int c = 0; c < 10; ++c) r[c] = vals[c];
    }
    __syncthreads();

    // cross-wave sum: thread (c=wid, l=lane) -> part[sb][c][qg*64+l]
    {
        const int c = wid, l = lane;
        float s = 0.0f;
#pragma unroll
        for (int ww = 0; ww < NWAVE; ++ww) s += red[(size_t)(ww * 64 + l) * 10 + c];
        const int gi = qg * QG + l;
        part[((size_t)sb * 10 + c) * N + gi] = s;
        if (tid < 64) {
            float sd = 0.0f;
#pragma unroll
            for (int ww = 0; ww < NWAVE; ++ww) sd += red[(size_t)(ww * 64 + l) * 10 + 8];
            part[((size_t)sb * 10 + 8) * N + gi] = sd;
        }
    }
}

// out[i,c] = (sum_sb num) / (sum_sb den) + 1e-6; coalesced row reads
__global__ __launch_bounds__(256) void nw_reduce(const float* __restrict__ part,
                                                 float* __restrict__ out,
                                                 int N, int nsb) {
    const int i = blockIdx.x * 256 + threadIdx.x;
    if (i >= N) return;
    float o[NCH];
#pragma unroll
    for (int c = 0; c < NCH; ++c) o[c] = 0.0f;
    float den = 0.0f;
    for (int sb = 0; sb < nsb; ++sb) {
        const float* base = part + (size_t)sb * 10 * N + i;
        den += base[8 * (size_t)N];
#pragma unroll
        for (int c = 0; c < NCH; ++c) o[c] += base[(size_t)c * N];
    }
    const float rd = 1.0f / den;
    float4* o4 = (float4*)(out + (size_t)i * NCH);
    o4[0] = make_float4(fmaf(o[0], rd, 1e-6f), fmaf(o[1], rd, 1e-6f),
                        fmaf(o[2], rd, 1e-6f), fmaf(o[3], rd, 1e-6f));
    o4[1] = make_float4(fmaf(o[4], rd, 1e-6f), fmaf(o[5], rd, 1e-6f),
                        fmaf(o[6], rd, 1e-6f), fmaf(o[7], rd, 1e-6f));
}

// generic fallback: one thread per query over all keys (exact math)
__global__ __launch_bounds__(256) void nw_full(const float* __restrict__ q,
                                               const float* __restrict__ k,
                                               const float* __restrict__ v,
                                               const float* __restrict__ kl,
                                               float* __restrict__ out,
                                               int N, int M) {
    const int i = blockIdx.x * 256 + threadIdx.x;
    if (i >= N) return;
    const float qx = q[i * 3 + 0], qy = q[i * 3 + 1], qz = q[i * 3 + 2];
    const float invL = 1.0f / kl[0];
    float num[NCH];
#pragma unroll
    for (int c = 0; c < NCH; ++c) num[c] = 0.0f;
    float den = 0.0f;
    for (int j = 0; j < M; ++j) {
        float dx = qx - k[j * 3 + 0], dy = qy - k[j * 3 + 1], dz = qz - k[j * 3 + 2];
        float d2 = fmaf(dx, dx, fmaf(dy, dy, dz * dz));
        float wt = nw_weight_exact(__builtin_amdgcn_sqrtf(d2) * invL);
        den += wt;
#pragma unroll
        for (int c = 0; c < NCH; ++c) num[c] = fmaf(wt, v[j * NCH + c], num[c]);
    }
    const float rden = 1.0f / den;
#pragma unroll
    for (int c = 0; c < NCH; ++c) out[i * NCH + c] = fmaf(num[c], rden, 1e-6f);
}

extern "C" void kernel_launch(void* const* d_in, const int* in_sizes, int n_in,
                              void* d_out, int out_size, void* d_ws, size_t ws_size,
                              hipStream_t stream) {
    const float* q  = (const float*)d_in[0];
    const float* k  = (const float*)d_in[1];
    const float* v  = (const float*)d_in[2];
    const float* kl = (const float*)d_in[3];
    float* out = (float*)d_out;

    const int N = in_sizes[0] / 3;   // 8192 queries
    const int M = in_sizes[1] / 3;   // 8192 keys

    const int nsb = (M + KSB - 1) / KSB;
    const size_t need_part  = (size_t)nsb * 10 * N * sizeof(float);
    const size_t kprep_sz   = (size_t)(M / 2) * 8 * sizeof(float);

    if ((N % QG) == 0 && (M % KSB) == 0 && ws_size >= need_part + kprep_sz) {
        float* part  = (float*)d_ws;
        float* kprep = (float*)((char*)d_ws + need_part);
        const int npair = M / 2;
        nw_prep<<<(npair + 255) / 256, 256, 0, stream>>>(k, kl, kprep, npair);
        dim3 grid(N / QG, nsb);
        nw_main<<<grid, TPB, 0, stream>>>(q, kprep, v, kl, part, N);
        nw_reduce<<<(N + 255) / 256, 256, 0, stream>>>(part, out, N, nsb);
    } else {
        nw_full<<<(N + 255) / 256, 256, 0, stream>>>(q, k, v, kl, out, N, M);
    }
}

// Round 14
// 51.104 us; speedup vs baseline: 1.1236x; 1.1236x over previous
//
#include <hip/hip_runtime.h>

// NW kernel regression via MFMA 32x32x16: out = (W @ [V|1]) -> num/den + 1e-6
// W[i,j] = max(0,(2+cos(2*pi*d))*(1-d)/3 + sin(2*pi*d)/(2*pi)), d=|q_i-k_j|/L
//
// Round-14: f32-throughput model (validated r11/r13) says acc = 9 of ~16
// ops/key -> move it to the matrix pipe; weight eval stays VALU+LUT.
//  - mfma_f32_32x32x16_f16: 2 k-groups -> a 16-key tile = 64 prescaled SGPRs,
//    k delivered via s_load (uniform addr), per-group select = 1 v_cndmask per
//    component (r12's failure was per-lane k VMEM; this kills it).
//  - kprep[key] = {-2ssL*x, -2ssL*y, -2ssL*z, ssL*|k|^2 + 0.5}, ssL=invL^2*LUTN
//    -> fidx = qx*KX+qy*KY+qz*KZ+(KW+q2off): 4 VALU + min + cvt + 1 LDS gather.
//  - B-frag: V fp16, ch8 = 1.0 (denominator as 9th GEMM column) — r12-proven.
//  - D-frag (col=lane&31=ch, row=(reg&3)+8*(reg>>2)+4*(lane>>5)) stores
//    partials directly; nw_reduce sums splits and divides.

typedef _Float16 h8 __attribute__((ext_vector_type(8)));
typedef float f32x16 __attribute__((ext_vector_type(16)));
typedef float f32x4 __attribute__((ext_vector_type(4)));

#define NCH 8
#define TPB 512        // 8 waves
#define QPB 256        // 8 waves x 32 query-rows
#define KSB 256        // keys per split = 16 MFMA tiles (K=16)
#define NTILE (KSB / 16)
#define LUTN 4096

__device__ __forceinline__ float nw_weight_exact(float cd) {
    float r  = __builtin_amdgcn_fractf(cd);
    float sn = __builtin_amdgcn_sinf(r);
    float cs = __builtin_amdgcn_cosf(r);
    float t  = (1.0f - cd) * (1.0f / 3.0f);
    float wt = fmaf(sn, 0.15915494309189535f, fmaf(cs, t, t + t));
    return fmaxf(wt, 0.0f);
}

// prep: kprep[key] (prescaled float4) and vfrag (fp16 B-fragments, ch8=1)
__global__ __launch_bounds__(256) void nw_prep(const float* __restrict__ k,
                                               const float* __restrict__ v,
                                               const float* __restrict__ kl,
                                               float4* __restrict__ kprep,
                                               h8* __restrict__ vfrag,
                                               int M) {
    const int idx = blockIdx.x * 256 + threadIdx.x;
    const float iL = 1.0f / kl[0];
    const float ssL = iL * iL * (float)LUTN;
    if (idx < M) {
        const float x = k[(size_t)idx * 3 + 0];
        const float y = k[(size_t)idx * 3 + 1];
        const float z = k[(size_t)idx * 3 + 2];
        float4 o;
        o.x = -2.0f * ssL * x;
        o.y = -2.0f * ssL * y;
        o.z = -2.0f * ssL * z;
        o.w = ssL * fmaf(x, x, fmaf(y, y, z * z)) + 0.5f;
        kprep[idx] = o;
    }
    const int nfrag = (M / 16) * 64;
    if (idx < nfrag) {
        const int kt = idx >> 6, l = idx & 63;
        const int ch = l & 31, g = l >> 5;
        h8 o;
#pragma unroll
        for (int j = 0; j < 8; ++j) {
            const int key = kt * 16 + g * 8 + j;
            const float val = (ch < 8) ? v[(size_t)key * 8 + ch]
                                       : (ch == 8 ? 1.0f : 0.0f);
            o[j] = (_Float16)val;
        }
        vfrag[idx] = o;
    }
}

__global__ __launch_bounds__(TPB) void nw_main(const float* __restrict__ q,
                                               const float4* __restrict__ kprep,
                                               const h8* __restrict__ vfrag,
                                               const float* __restrict__ kl,
                                               float* __restrict__ part,
                                               int N) {
    __shared__ float lutw[LUTN + 1];

    const int tid  = threadIdx.x;
    const int lane = tid & 63;
    const int wid  = tid >> 6;
    const int qg   = blockIdx.x;
    const int sb   = blockIdx.y;

    const float iL = 1.0f / kl[0];
    const float ssL = iL * iL * (float)LUTN;

    for (int e = tid; e <= LUTN; e += TPB)
        lutw[e] = nw_weight_exact(__builtin_amdgcn_sqrtf((float)e * (1.0f / (float)LUTN)));
    __syncthreads();

    const int row = lane & 31;
    const bool hi = lane >= 32;
    const int qi = qg * QPB + wid * 32 + row;
    const float qx = q[qi * 3 + 0];
    const float qy = q[qi * 3 + 1];
    const float qz = q[qi * 3 + 2];
    const float q2off = ssL * fmaf(qx, qx, fmaf(qy, qy, qz * qz));

    const float4* __restrict__ kq = kprep + (size_t)sb * KSB;     // uniform -> s_load
    const h8* __restrict__ vfq = vfrag + (size_t)sb * NTILE * 64;

    f32x16 acc;
#pragma unroll
    for (int e = 0; e < 16; ++e) acc[e] = 0.0f;

    for (int t = 0; t < NTILE; ++t) {
        const h8 vf = vfq[t * 64 + lane];     // per-lane 16B VMEM (L2-hot)
        h8 af;
#pragma unroll
        for (int j = 0; j < 8; ++j) {
            const float4 ka = kq[t * 16 + j];       // SGPRs (group 0 key)
            const float4 kb = kq[t * 16 + 8 + j];   // SGPRs (group 1 key)
            const float kx = hi ? kb.x : ka.x;      // v_cndmask
            const float ky = hi ? kb.y : ka.y;
            const float kz = hi ? kb.z : ka.z;
            const float kw = hi ? kb.w : ka.w;
            float fidx = fmaf(qx, kx, fmaf(qy, ky, fmaf(qz, kz, kw + q2off)));
            fidx = fminf(fidx, (float)LUTN);
            af[j] = (_Float16)lutw[(unsigned)fidx];  // NN LUT gather
        }
        acc = __builtin_amdgcn_mfma_f32_32x32x16_f16(af, vf, acc, 0, 0, 0);
    }

    // D: col = lane&31 = channel, row = (reg&3) + 8*(reg>>2) + 4*(lane>>5)
    const int ch = lane & 31;
    if (ch < 9) {
        const int g = hi ? 1 : 0;
#pragma unroll
        for (int rq = 0; rq < 4; ++rq) {
            f32x4 o = {acc[4 * rq + 0], acc[4 * rq + 1], acc[4 * rq + 2], acc[4 * rq + 3]};
            const int gi = qg * QPB + wid * 32 + 8 * rq + 4 * g;
            *(f32x4*)(part + ((size_t)sb * 10 + ch) * N + gi) = o;
        }
    }
}

// out[i,c] = (sum_sb num) / (sum_sb den) + 1e-6; coalesced row reads
__global__ __launch_bounds__(256) void nw_reduce(const float* __restrict__ part,
                                                 float* __restrict__ out,
                                                 int N, int nsb) {
    const int i = blockIdx.x * 256 + threadIdx.x;
    if (i >= N) return;
    float o[NCH];
#pragma unroll
    for (int c = 0; c < NCH; ++c) o[c] = 0.0f;
    float den = 0.0f;
    for (int sb = 0; sb < nsb; ++sb) {
        const float* base = part + (size_t)sb * 10 * N + i;
        den += base[8 * (size_t)N];
#pragma unroll
        for (int c = 0; c < NCH; ++c) o[c] += base[(size_t)c * N];
    }
    const float rd = 1.0f / den;
    float4* o4 = (float4*)(out + (size_t)i * NCH);
    o4[0] = make_float4(fmaf(o[0], rd, 1e-6f), fmaf(o[1], rd, 1e-6f),
                        fmaf(o[2], rd, 1e-6f), fmaf(o[3], rd, 1e-6f));
    o4[1] = make_float4(fmaf(o[4], rd, 1e-6f), fmaf(o[5], rd, 1e-6f),
                        fmaf(o[6], rd, 1e-6f), fmaf(o[7], rd, 1e-6f));
}

// generic fallback: one thread per query over all keys (exact math)
__global__ __launch_bounds__(256) void nw_full(const float* __restrict__ q,
                                               const float* __restrict__ k,
                                               const float* __restrict__ v,
                                               const float* __restrict__ kl,
                                               float* __restrict__ out,
                                               int N, int M) {
    const int i = blockIdx.x * 256 + threadIdx.x;
    if (i >= N) return;
    const float qx = q[i * 3 + 0], qy = q[i * 3 + 1], qz = q[i * 3 + 2];
    const float invL = 1.0f / kl[0];
    float num[NCH];
#pragma unroll
    for (int c = 0; c < NCH; ++c) num[c] = 0.0f;
    float den = 0.0f;
    for (int j = 0; j < M; ++j) {
        float dx = qx - k[j * 3 + 0], dy = qy - k[j * 3 + 1], dz = qz - k[j * 3 + 2];
        float d2 = fmaf(dx, dx, fmaf(dy, dy, dz * dz));
        float wt = nw_weight_exact(__builtin_amdgcn_sqrtf(d2) * invL);
        den += wt;
#pragma unroll
        for (int c = 0; c < NCH; ++c) num[c] = fmaf(wt, v[j * NCH + c], num[c]);
    }
    const float rden = 1.0f / den;
#pragma unroll
    for (int c = 0; c < NCH; ++c) out[i * NCH + c] = fmaf(num[c], rden, 1e-6f);
}

extern "C" void kernel_launch(void* const* d_in, const int* in_sizes, int n_in,
                              void* d_out, int out_size, void* d_ws, size_t ws_size,
                              hipStream_t stream) {
    const float* q  = (const float*)d_in[0];
    const float* k  = (const float*)d_in[1];
    const float* v  = (const float*)d_in[2];
    const float* kl = (const float*)d_in[3];
    float* out = (float*)d_out;

    const int N = in_sizes[0] / 3;   // 8192 queries
    const int M = in_sizes[1] / 3;   // 8192 keys

    const int nsb = (M + KSB - 1) / KSB;
    const size_t part_sz  = (size_t)nsb * 10 * N * sizeof(float);
    const size_t kprep_sz = (size_t)M * sizeof(float4);
    const size_t vfrag_sz = (size_t)(M / 16) * 64 * sizeof(h8);

    if ((N % QPB) == 0 && (M % KSB) == 0 && ws_size >= part_sz + kprep_sz + vfrag_sz) {
        float*  part  = (float*)d_ws;
        float4* kprep = (float4*)((char*)d_ws + part_sz);
        h8*     vfrag = (h8*)((char*)d_ws + part_sz + kprep_sz);
        const int nprep = (M / 16) * 64;   // >= M
        nw_prep<<<(nprep + 255) / 256, 256, 0, stream>>>(k, v, kl, kprep, vfrag, M);
        dim3 grid(N / QPB, nsb);
        nw_main<<<grid, TPB, 0, stream>>>(q, kprep, vfrag, kl, part, N);
        nw_reduce<<<(N + 255) / 256, 256, 0, stream>>>(part, out, N, nsb);
    } else {
        nw_full<<<(N + 255) / 256, 256, 0, stream>>>(q, k, v, kl, out, N, M);
    }
}

// Round 15
// 34.068 us; speedup vs baseline: 1.6856x; 1.5001x over previous
//
#include <hip/hip_runtime.h>

// NW kernel regression, double-MFMA (attention structure):
//   MFMA1: fidx = ssL*(|q|^2+|k|^2-2q.k)+0.5 as rank-13 f16 hi/lo GEMM
//   VALU:  w = lutw[clamp(fidx)]  (NN 4096-cell LUT in s-domain, 1 gather/key)
//   MFMA2: [num|den] = W @ [V|1]  (ch8 = 1.0 denominator column)
// Conventions (proven r12/r14 by passing absmax):
//   A-frag 32x32x16: A[row=lane&31][slot=(lane>>5)*8+j]
//   B-frag:          B[slot=(lane>>5)*8+j][col=lane&31]
//   D:               col=lane&31, row=(reg&3)+8*(reg>>2)+4*(lane>>5)
// MFMA1 D-reg r on lane (hi=lane>>5) holds key (r&3)+8*(r>>2)+4*hi, so MFMA2's
// A-slot s=g*8+j maps to key perm(g,j)=(j&3)+8*(j>>2)+4*g (+16 for set b) —
// folded into vfrag packing by nw_prep.
// hi/lo split exactness: f16 products are exact in f32 accum; dropped lo*lo
// terms <= ~2e-3 LUT cells; NN quantization +-0.5 cell dominates (absmax
// ~5e-4, threshold 2.02e-3 — r8/r9/r14 measured).

typedef _Float16 h8 __attribute__((ext_vector_type(8)));
typedef float f32x16 __attribute__((ext_vector_type(16)));
typedef float f32x4 __attribute__((ext_vector_type(4)));

#define NCH 8
#define TPB 512        // 8 waves
#define QPB 256        // 8 waves x 32 query-rows
#define KSB 256        // keys per split = 8 tiles of 32
#define NTILE (KSB / 32)
#define LUTN 4096

__device__ __forceinline__ float nw_weight_exact(float cd) {
    float r  = __builtin_amdgcn_fractf(cd);
    float sn = __builtin_amdgcn_sinf(r);
    float cs = __builtin_amdgcn_cosf(r);
    float t  = (1.0f - cd) * (1.0f / 3.0f);
    float wt = fmaf(sn, 0.15915494309189535f, fmaf(cs, t, t + t));
    return fmaxf(wt, 0.0f);
}

__device__ __forceinline__ void split16(float x, _Float16& h, _Float16& l) {
    h = (_Float16)x;
    l = (_Float16)(x - (float)h);
}

// kfrag[key*2+g][j]: A-side slots; vfrag[(tile*2+set)*64+lane]: B-side V-frags
__global__ __launch_bounds__(256) void nw_prep(const float* __restrict__ k,
                                               const float* __restrict__ v,
                                               const float* __restrict__ kl,
                                               h8* __restrict__ kfrag,
                                               h8* __restrict__ vfrag,
                                               int M) {
    const int idx = blockIdx.x * 256 + threadIdx.x;
    const float iL = 1.0f / kl[0];
    const float ssL = iL * iL * (float)LUTN;
    if (idx < M) {
        const float x = k[(size_t)idx * 3 + 0];
        const float y = k[(size_t)idx * 3 + 1];
        const float z = k[(size_t)idx * 3 + 2];
        const float cx = -2.0f * ssL * x, cy = -2.0f * ssL * y, cz = -2.0f * ssL * z;
        const float k2 = ssL * fmaf(x, x, fmaf(y, y, z * z));
        _Float16 cxh, cxl, cyh, cyl, czh, czl, k2h, k2l;
        split16(cx, cxh, cxl); split16(cy, cyh, cyl);
        split16(cz, czh, czl); split16(k2, k2h, k2l);
        h8 lo = {cxh, cxh, cxl, cyh, cyh, cyl, czh, czh};
        h8 hi = {czl, k2h, k2l, (_Float16)1.0f, (_Float16)1.0f,
                 (_Float16)0.0f, (_Float16)0.0f, (_Float16)0.0f};
        kfrag[idx * 2 + 0] = lo;
        kfrag[idx * 2 + 1] = hi;
    }
    const int nv = (M / 32) * 128;   // tiles * 2 sets * 64 lanes
    if (idx < nv) {
        const int t = idx >> 7, r = idx & 127;
        const int set = r >> 6, l = r & 63;
        const int ch = l & 31, g = l >> 5;
        h8 o;
#pragma unroll
        for (int j = 0; j < 8; ++j) {
            const int key = t * 32 + set * 16 + ((j & 3) + 8 * (j >> 2) + 4 * g);
            const float val = (ch < 8) ? v[(size_t)key * 8 + ch]
                                       : (ch == 8 ? 1.0f : 0.0f);
            o[j] = (_Float16)val;
        }
        vfrag[(size_t)(t * 2 + set) * 64 + l] = o;
    }
}

__global__ __launch_bounds__(TPB) void nw_main(const float* __restrict__ q,
                                               const h8* __restrict__ kfrag,
                                               const h8* __restrict__ vfrag,
                                               const float* __restrict__ kl,
                                               float* __restrict__ part,
                                               int N) {
    __shared__ float lutw[LUTN + 1];

    const int tid  = threadIdx.x;
    const int lane = tid & 63;
    const int wid  = tid >> 6;
    const int qg   = blockIdx.x;
    const int sb   = blockIdx.y;

    const float iL = 1.0f / kl[0];
    const float ssL = iL * iL * (float)LUTN;

    for (int e = tid; e <= LUTN; e += TPB)
        lutw[e] = nw_weight_exact(__builtin_amdgcn_sqrtf((float)e * (1.0f / (float)LUTN)));
    __syncthreads();

    const int row = lane & 31;
    const int g   = lane >> 5;
    const int qi  = qg * QPB + wid * 32 + row;
    const float qx = q[qi * 3 + 0];
    const float qy = q[qi * 3 + 1];
    const float qz = q[qi * 3 + 2];
    const float q2 = ssL * fmaf(qx, qx, fmaf(qy, qy, qz * qz)) + 0.5f;

    _Float16 qxh, qxl, qyh, qyl, qzh, qzl, q2h, q2l;
    split16(qx, qxh, qxl); split16(qy, qyh, qyl);
    split16(qz, qzh, qzl); split16(q2, q2h, q2l);
    const _Float16 one = (_Float16)1.0f, zer = (_Float16)0.0f;
    // B-frag (constant across tiles): g=0 slots0..7, g=1 slots8..15
    h8 qf;
    qf[0] = g ? qzh : qxh;
    qf[1] = g ? one : qxl;
    qf[2] = g ? one : qxh;
    qf[3] = g ? q2h : qyh;
    qf[4] = g ? q2l : qyl;
    qf[5] = g ? zer : qyh;
    qf[6] = g ? zer : qzh;
    qf[7] = g ? zer : qzl;

    const h8* __restrict__ kfq = kfrag + (size_t)(sb * KSB) * 2;
    const h8* __restrict__ vfq = vfrag + (size_t)(sb * NTILE) * 128;

    f32x16 acc;
#pragma unroll
    for (int e = 0; e < 16; ++e) acc[e] = 0.0f;
    f32x16 zacc;
#pragma unroll
    for (int e = 0; e < 16; ++e) zacc[e] = 0.0f;

    for (int t = 0; t < NTILE; ++t) {
        const h8 ka  = kfq[(size_t)(t * 32 + row) * 2 + g];   // A1: per-lane 16B
        const h8 vfa = vfq[(size_t)(t * 2 + 0) * 64 + lane];
        const h8 vfb = vfq[(size_t)(t * 2 + 1) * 64 + lane];

        const f32x16 s = __builtin_amdgcn_mfma_f32_32x32x16_f16(ka, qf, zacc, 0, 0, 0);

        h8 afa, afb;
#pragma unroll
        for (int r = 0; r < 8; ++r) {
            float fx = fmaxf(fminf(s[r], (float)LUTN), 0.0f);
            afa[r] = (_Float16)lutw[(unsigned)fx];
        }
#pragma unroll
        for (int r = 0; r < 8; ++r) {
            float fx = fmaxf(fminf(s[8 + r], (float)LUTN), 0.0f);
            afb[r] = (_Float16)lutw[(unsigned)fx];
        }
        acc = __builtin_amdgcn_mfma_f32_32x32x16_f16(afa, vfa, acc, 0, 0, 0);
        acc = __builtin_amdgcn_mfma_f32_32x32x16_f16(afb, vfb, acc, 0, 0, 0);
    }

    // D: col=lane&31=channel, row=(reg&3)+8*(reg>>2)+4*g = local query
    const int ch = lane & 31;
    if (ch < 9) {
#pragma unroll
        for (int rq = 0; rq < 4; ++rq) {
            f32x4 o = {acc[4 * rq + 0], acc[4 * rq + 1], acc[4 * rq + 2], acc[4 * rq + 3]};
            const int gi = qg * QPB + wid * 32 + 8 * rq + 4 * g;
            *(f32x4*)(part + ((size_t)sb * 10 + ch) * N + gi) = o;
        }
    }
}

// out[i,c] = (sum_sb num) / (sum_sb den) + 1e-6; coalesced row reads
__global__ __launch_bounds__(256) void nw_reduce(const float* __restrict__ part,
                                                 float* __restrict__ out,
                                                 int N, int nsb) {
    const int i = blockIdx.x * 256 + threadIdx.x;
    if (i >= N) return;
    float o[NCH];
#pragma unroll
    for (int c = 0; c < NCH; ++c) o[c] = 0.0f;
    float den = 0.0f;
    for (int sb = 0; sb < nsb; ++sb) {
        const float* base = part + (size_t)sb * 10 * N + i;
        den += base[8 * (size_t)N];
#pragma unroll
        for (int c = 0; c < NCH; ++c) o[c] += base[(size_t)c * N];
    }
    const float rd = 1.0f / den;
    float4* o4 = (float4*)(out + (size_t)i * NCH);
    o4[0] = make_float4(fmaf(o[0], rd, 1e-6f), fmaf(o[1], rd, 1e-6f),
                        fmaf(o[2], rd, 1e-6f), fmaf(o[3], rd, 1e-6f));
    o4[1] = make_float4(fmaf(o[4], rd, 1e-6f), fmaf(o[5], rd, 1e-6f),
                        fmaf(o[6], rd, 1e-6f), fmaf(o[7], rd, 1e-6f));
}

// generic fallback: one thread per query over all keys (exact math)
__global__ __launch_bounds__(256) void nw_full(const float* __restrict__ q,
                                               const float* __restrict__ k,
                                               const float* __restrict__ v,
                                               const float* __restrict__ kl,
                                               float* __restrict__ out,
                                               int N, int M) {
    const int i = blockIdx.x * 256 + threadIdx.x;
    if (i >= N) return;
    const float qx = q[i * 3 + 0], qy = q[i * 3 + 1], qz = q[i * 3 + 2];
    const float invL = 1.0f / kl[0];
    float num[NCH];
#pragma unroll
    for (int c = 0; c < NCH; ++c) num[c] = 0.0f;
    float den = 0.0f;
    for (int j = 0; j < M; ++j) {
        float dx = qx - k[j * 3 + 0], dy = qy - k[j * 3 + 1], dz = qz - k[j * 3 + 2];
        float d2 = fmaf(dx, dx, fmaf(dy, dy, dz * dz));
        float wt = nw_weight_exact(__builtin_amdgcn_sqrtf(d2) * invL);
        den += wt;
#pragma unroll
        for (int c = 0; c < NCH; ++c) num[c] = fmaf(wt, v[j * NCH + c], num[c]);
    }
    const float rden = 1.0f / den;
#pragma unroll
    for (int c = 0; c < NCH; ++c) out[i * NCH + c] = fmaf(num[c], rden, 1e-6f);
}

extern "C" void kernel_launch(void* const* d_in, const int* in_sizes, int n_in,
                              void* d_out, int out_size, void* d_ws, size_t ws_size,
                              hipStream_t stream) {
    const float* q  = (const float*)d_in[0];
    const float* k  = (const float*)d_in[1];
    const float* v  = (const float*)d_in[2];
    const float* kl = (const float*)d_in[3];
    float* out = (float*)d_out;

    const int N = in_sizes[0] / 3;   // 8192 queries
    const int M = in_sizes[1] / 3;   // 8192 keys

    const int nsb = (M + KSB - 1) / KSB;
    const size_t part_sz  = (size_t)nsb * 10 * N * sizeof(float);
    const size_t kfrag_sz = (size_t)M * 2 * sizeof(h8);
    const size_t vfrag_sz = (size_t)(M / 32) * 128 * sizeof(h8);

    if ((N % QPB) == 0 && (M % KSB) == 0 && ws_size >= part_sz + kfrag_sz + vfrag_sz) {
        float* part  = (float*)d_ws;
        h8*    kfrag = (h8*)((char*)d_ws + part_sz);
        h8*    vfrag = (h8*)((char*)d_ws + part_sz + kfrag_sz);
        const int nprep = (M / 32) * 128;   // >= M
        nw_prep<<<(nprep + 255) / 256, 256, 0, stream>>>(k, v, kl, kfrag, vfrag, M);
        dim3 grid(N / QPB, nsb);
        nw_main<<<grid, TPB, 0, stream>>>(q, kfrag, vfrag, kl, part, N);
        nw_reduce<<<(N + 255) / 256, 256, 0, stream>>>(part, out, N, nsb);
    } else {
        nw_full<<<(N + 255) / 256, 256, 0, stream>>>(q, k, v, kl, out, N, M);
    }
}